// Round 7
// baseline (325.424 us; speedup 1.0000x reference)
//
#include <hip/hip_runtime.h>
#include <hip/hip_bf16.h>

// ChebyshevKANLayer: y[b,o] = sum_{i,j} T_j(xhat[b,i]) * C[i,o,j]
// R7: A never exists in HBM. T0 folded into bias (R6). GEMM (M=8192, N=1024,
// K=1024*8) builds its A-tile ON THE FLY from xnT (fp32 normalized-transposed
// x, 32 MB, L3-resident): per BK=64 iter each thread runs 4 Chebyshev chains
// and writes 4 swizzled uint4 to LDS. Tile 128x64, grid (16,64)=1024 blocks =
// 4 blocks/CU = 16 waves/CU. B via global_load_lds(16B), XOR-swizzled LDS both.
// ws: bias 4KB | stats 64KB | xnT 32MB | B^T 16.8MB  (~49 MB total)

typedef __attribute__((ext_vector_type(8))) short bf16x8s;   // MFMA A/B frag (4 VGPRs)
typedef __attribute__((ext_vector_type(4))) float f32x4;     // MFMA C/D frag

constexpr int BROWS = 8192;
constexpr int IDIM  = 1024;
constexpr int ODIM  = 1024;
constexpr int DEG1  = 9;
constexpr int KP    = 8;             // stored degrees 1..8 per input i
constexpr int KD    = IDIM * KP;     // 8192

__device__ __forceinline__ ushort f2bf(float f) {
  return ((__hip_bfloat16_raw)__float2bfloat16(f)).x;
}
__device__ __forceinline__ uint packbf(float a, float b) {
  return (uint)f2bf(a) | ((uint)f2bf(b) << 16);
}

// async global->LDS, 16 B per lane. LDS dst MUST be wave-uniform base + lane*16.
__device__ __forceinline__ void gload_lds16(const void* g, void* l) {
  __builtin_amdgcn_global_load_lds(
      (const __attribute__((address_space(1))) unsigned int*)g,
      (__attribute__((address_space(3))) unsigned int*)l, 16, 0, 0);
}

// ---------- 1. per-row min/max -> (scale, offset); block 0 also zeroes bias ----------
__global__ __launch_bounds__(256) void rowstats_kernel(const float* __restrict__ x,
                                                       float* __restrict__ stats,
                                                       float* __restrict__ bias) {
  const int row  = blockIdx.x * 4 + (threadIdx.x >> 6);   // one wave per row
  const int lane = threadIdx.x & 63;
  const float4* xr = (const float4*)(x + (size_t)row * IDIM);
  float mn = 3.402823466e38f, mx = -3.402823466e38f;
#pragma unroll
  for (int c = 0; c < 4; ++c) {
    float4 v = xr[lane + c * 64];
    mn = fminf(mn, fminf(fminf(v.x, v.y), fminf(v.z, v.w)));
    mx = fmaxf(mx, fmaxf(fmaxf(v.x, v.y), fmaxf(v.z, v.w)));
  }
#pragma unroll
  for (int off = 32; off >= 1; off >>= 1) {
    mn = fminf(mn, __shfl_xor(mn, off));
    mx = fmaxf(mx, __shfl_xor(mx, off));
  }
  if (lane == 0) {
    float inv = 2.0f / (mx - mn);
    stats[row * 2 + 0] = inv;                 // scale
    stats[row * 2 + 1] = -mn * inv - 1.0f;    // offset
  }
  if (blockIdx.x == 0) {                      // zero bias (ws re-poisoned each call)
#pragma unroll
    for (int c = 0; c < 4; ++c) bias[c * 256 + threadIdx.x] = 0.0f;
  }
}

// ---------- 2. xnT[i][r] = scale[r]*x[r][i]+offset[r], 64x64 LDS transpose ----------
__global__ __launch_bounds__(256) void transpose_norm_kernel(const float* __restrict__ x,
                                                             const float* __restrict__ stats,
                                                             float* __restrict__ xnT) {
  __shared__ float tile[64][65];               // +1 pad: conflict-free transpose
  const int i0 = blockIdx.x * 64;
  const int r0 = blockIdx.y * 64;
  const int t  = threadIdx.x;
  const int lc = t & 63;
  const int p4 = t >> 6;
#pragma unroll
  for (int rr = p4; rr < 64; rr += 4) {        // read: lanes vary i -> coalesced
    const float sc = stats[(r0 + rr) * 2 + 0];
    const float of = stats[(r0 + rr) * 2 + 1];
    tile[rr][lc] = fmaf(sc, x[(size_t)(r0 + rr) * IDIM + i0 + lc], of);
  }
  __syncthreads();
#pragma unroll
  for (int ii = p4; ii < 64; ii += 4)          // write: lanes vary r -> coalesced
    xnT[(size_t)(i0 + ii) * BROWS + r0 + lc] = tile[lc][ii];
}

// ---------- 3. B^T[o][i*8+d'] = C[i][o][d'+1] bf16; j==0 -> fp32 bias ----------
__global__ __launch_bounds__(256) void build_b_kernel(const float* __restrict__ coeffs,
                                                      ushort* __restrict__ B2T,
                                                      float* __restrict__ bias) {
  __shared__ __align__(16) ushort tile[64 * 256];          // 32 KB [o_l][i_l*8+d']
  __shared__ float lb[64];
  const int i0 = blockIdx.x * 32;
  const int o0 = blockIdx.y * 64;
  const int t  = threadIdx.x;
  if (t < 64) lb[t] = 0.0f;
  __syncthreads();
  for (int idx = t; idx < 18432; idx += 256) {             // coalesced float reads
    const int i_l = idx / 576;                             // 576 = 64*9
    const int rem = idx - i_l * 576;                       // = o_l*9 + j
    const float v = coeffs[((size_t)(i0 + i_l) * ODIM + o0) * DEG1 + rem];
    const int o_l = rem / 9;
    const int j   = rem - o_l * 9;
    if (j == 0) atomicAdd(&lb[o_l], v);                    // exact fp32 bias path
    else tile[o_l * 256 + i_l * KP + (j - 1)] = f2bf(v);
  }
  __syncthreads();
  for (int idx = t; idx < 2048; idx += 256) {              // coalesced uint4 writes
    const int o_l = idx >> 5;
    const int w   = idx & 31;
    uint4* gdst = (uint4*)(B2T + (size_t)(o0 + o_l) * KD + i0 * KP);
    gdst[w] = ((const uint4*)tile)[idx];
  }
  if (t < 64) atomicAdd(&bias[o0 + t], lb[t]);             // device-scope fp32 add
}

// ---------- 4. fused GEMM: 128x64 tile, BK=64, on-the-fly A, swizzled LDS ----------
// Thread t: A-builder identity (arow = t&127, ahi = t>>7) computes Chebyshev
// T1..T8 for 4 i-slots per iter, packs to one uint4 each, ds_writes at
// swizzled chunk (i_l ^ (arow&7)). B staged via global_load_lds with the same
// XOR permutation on the GLOBAL chunk. Frag reads: chunk (kh*4+quad)^(c16&7).
__global__ __launch_bounds__(256, 4) void gemm_kernel(const float* __restrict__ xnT,
                                                      const ushort* __restrict__ B2T,
                                                      const float* __restrict__ bias,
                                                      float* __restrict__ out) {
  constexpr int BK = 64;
  __shared__ __align__(16) ushort As[128 * BK];   // 16 KB
  __shared__ __align__(16) ushort Bs[64 * BK];    //  8 KB
  const int t    = threadIdx.x;
  const int wave = t >> 6;
  const int lane = t & 63;
  const int wr   = wave & 1;                      // row half (64 rows)
  const int wc   = wave >> 1;                     // col half (32 cols)
  const int c16  = lane & 15;
  const int quad = lane >> 4;
  const int rowBase = blockIdx.y * 128;
  const int colBase = blockIdx.x * 64;

  // B staging: rows colBase + srow + rr*32, global chunk XOR-permuted
  const int srow = t >> 3;                        // 0..31
  const int scol = (t & 7) ^ (srow & 7);
  const ushort* bB = B2T + (size_t)(colBase + srow) * KD + scol * 8;
  ushort* lB = Bs + t * 8;                        // wave-uniform base + lane*16B

  // A build: arow = t&127; i-slots i_l = 2c + ahi, c = 0..3
  const int arow = t & 127;
  const int ahi  = t >> 7;
  const float* xbase = xnT + rowBase + arow;      // lanes -> consecutive rows

  float xv[4];                                    // prefetched xn for this iter
#pragma unroll
  for (int c = 0; c < 4; ++c) xv[c] = xbase[(size_t)(2 * c + ahi) * BROWS];

  f32x4 acc[4][2];
#pragma unroll
  for (int a = 0; a < 4; ++a)
#pragma unroll
    for (int b = 0; b < 2; ++b) acc[a][b] = (f32x4){0.f, 0.f, 0.f, 0.f};

  for (int ip = 0; ip < KD / BK; ++ip) {          // 128 iters
    __syncthreads();                              // prev tile fully consumed
    gload_lds16(bB + (size_t)0 * KD + ip * BK, lB);
    gload_lds16(bB + (size_t)32 * KD + ip * BK, lB + 2048);

#pragma unroll
    for (int c = 0; c < 4; ++c) {                 // 4 independent Chebyshev chains
      const float xn = xv[c];
      const float tx = xn + xn;
      const float T2 = fmaf(tx, xn, -1.0f);
      const float T3 = fmaf(tx, T2, -xn);
      const float T4 = fmaf(tx, T3, -T2);
      const float T5 = fmaf(tx, T4, -T3);
      const float T6 = fmaf(tx, T5, -T4);
      const float T7 = fmaf(tx, T6, -T5);
      const float T8 = fmaf(tx, T7, -T6);
      const int i_l = 2 * c + ahi;
      uint4 w = {packbf(xn, T2), packbf(T3, T4), packbf(T5, T6), packbf(T7, T8)};
      *(uint4*)&As[arow * BK + ((i_l ^ (arow & 7)) * 8)] = w;   // swizzled, conflict-free
    }
    if (ip + 1 < KD / BK) {                       // prefetch next iter's xn
#pragma unroll
      for (int c = 0; c < 4; ++c)
        xv[c] = xbase[((size_t)(ip + 1) * 8 + 2 * c + ahi) * BROWS];
    }
    __syncthreads();                              // drains vmcnt + lgkmcnt

#pragma unroll
    for (int kh = 0; kh < 2; ++kh) {              // sequential k-halves: low VGPR
      const int cx = ((kh * 4 + quad) ^ (c16 & 7)) * 8;   // swizzled chunk
      bf16x8s afr[4], bfr[2];
#pragma unroll
      for (int tm = 0; tm < 4; ++tm)              // A frag: m = lane&15, k = quad*8+j
        afr[tm] = *(const bf16x8s*)&As[(wr * 64 + tm * 16 + c16) * BK + cx];
#pragma unroll
      for (int tn = 0; tn < 2; ++tn)
        bfr[tn] = *(const bf16x8s*)&Bs[(wc * 32 + tn * 16 + c16) * BK + cx];
#pragma unroll
      for (int tm = 0; tm < 4; ++tm)
#pragma unroll
        for (int tn = 0; tn < 2; ++tn)
          acc[tm][tn] = __builtin_amdgcn_mfma_f32_16x16x32_bf16(afr[tm], bfr[tn],
                                                                acc[tm][tn], 0, 0, 0);
    }
  }

  // epilogue: add bias, store.  C/D map: col = lane&15, row = quad*4 + r
#pragma unroll
  for (int tm = 0; tm < 4; ++tm)
#pragma unroll
    for (int tn = 0; tn < 2; ++tn) {
      const int row0 = rowBase + wr * 64 + tm * 16 + quad * 4;
      const int col  = colBase + wc * 32 + tn * 16 + c16;
      const float bv = bias[col];
#pragma unroll
      for (int r = 0; r < 4; ++r)
        out[(size_t)(row0 + r) * ODIM + col] = acc[tm][tn][r] + bv;
    }
}

extern "C" void kernel_launch(void* const* d_in, const int* in_sizes, int n_in,
                              void* d_out, int out_size, void* d_ws, size_t ws_size,
                              hipStream_t stream) {
  const float* x      = (const float*)d_in[0];   // [8192,1024] fp32
  const float* coeffs = (const float*)d_in[1];   // [1024,1024,9] fp32
  float* out = (float*)d_out;                    // [8192,1024] fp32

  char* ws = (char*)d_ws;
  float*  bias  = (float*)ws;                                       // 4 KB (64K slot)
  float*  stats = (float*)(ws + 65536);                             // 64 KB slot
  float*  xnT   = (float*)(ws + 131072);                            // 32 MB
  ushort* B2T   = (ushort*)(ws + 131072 + (size_t)IDIM * BROWS * 4);// 16.8 MB
  // total ws: ~49 MB

  rowstats_kernel<<<BROWS / 4, 256, 0, stream>>>(x, stats, bias);
  transpose_norm_kernel<<<dim3(IDIM / 64, BROWS / 64), 256, 0, stream>>>(x, stats, xnT);
  build_b_kernel<<<dim3(IDIM / 32, ODIM / 64), 256, 0, stream>>>(coeffs, B2T, bias);
  gemm_kernel<<<dim3(ODIM / 64, BROWS / 128), 256, 0, stream>>>(xnT, B2T, bias, out);
}